// Round 11
// baseline (760.060 us; speedup 1.0000x reference)
//
#include <hip/hip_runtime.h>
#include <stdint.h>

#define N_ 4096
#define B_ 1024
#define W_ 128          // N/32 neuron-words (colAny bitmasks)
#define NSTEPS_ 10
#define DEG_SLOTS 40    // padded neighbor-list slots (deg ~ Poisson(12); P(>40) ~ 1e-11)
#define UNR 16          // static unrolled gather depth (sentinel-padded)
#define PAD_E ((uint32_t)(N_ * B_))   // sentinel -> byte offset of zero pad row
#define NBLK 1024

// ws layout (bytes):
//   r0nz   : 0      .. 5120      u32[NSTEPS][W]    bit n: pure-decay refr!=0 before step s
//   colAny : 5120   .. 11264     u32[NSTEPS+2][W]  rows 0,1 zero; step s ORs row s+2
//   bar    : 11264  .. 13568     u32[576]: 16 arrival ctrs at stride 32 (128B) + flag at [512]
//   deg    : 13568  .. 29952     u32[N]
//   nbr    : 29952  .. 685312    u32[N][DEG_SLOTS] entry = m*B (byte offset); sentinel N*B
//   sExp   : 685312 .. ~9.08MB   u8[2][(N+1)*B]    spike BYTES [n][b]; row N_ always zero
#define OFF_R0NZ   0
#define OFF_COLANY 5120
#define OFF_BAR    11264
#define OFF_DEG    13568
#define OFF_NBR    29952
#define OFF_SEXP   685312
#define SEXP_BUF   ((N_ + 1) * B_)

// build_k: neighbor lists from C; blocks 0..15 additionally do all one-time init.
__global__ __launch_bounds__(256) void build_k(const float* __restrict__ C,
                                               const float* __restrict__ refr_in,
                                               uint32_t* __restrict__ deg,
                                               uint32_t* __restrict__ nbr,
                                               uint32_t* __restrict__ r0nz,
                                               uint32_t* __restrict__ colAny,
                                               uint32_t* __restrict__ bar,
                                               uint32_t* __restrict__ pad0,
                                               uint32_t* __restrict__ pad1) {
    __shared__ uint32_t cnt;
    int tid = threadIdx.x;
    if (blockIdx.x < 16) {
        int i = blockIdx.x * 256 + tid;
        if (i < (NSTEPS_ + 2) * W_) {
            colAny[i] = 0u;
        } else if (i >= 1536 && i < 2112) {
            bar[i - 1536] = 0u;              // barrier counters + flag
        } else if (i >= 2112 && i < 2112 + W_) {
            int w = i - 2112;
            uint32_t bits[NSTEPS_];
            #pragma unroll
            for (int s = 0; s < NSTEPS_; ++s) bits[s] = 0u;
            for (int k = 0; k < 32; ++k) {
                float r = refr_in[w * 32 + k];
                #pragma unroll
                for (int s = 0; s < NSTEPS_; ++s) {
                    bits[s] |= (r != 0.0f ? 1u : 0u) << k;
                    r = fminf(fmaxf(r - 1.0f, 0.0f), 10.0f);
                }
            }
            #pragma unroll
            for (int s = 0; s < NSTEPS_; ++s) r0nz[s * W_ + w] = bits[s];
        } else if (i >= 2560 && i < 2816) {
            pad0[i - 2560] = 0u;             // zero pad row of sExp buf0
        } else if (i >= 2816 && i < 3072) {
            pad1[i - 2816] = 0u;             // zero pad row of sExp buf1
        }
    }
    int n = blockIdx.x;
    if (tid == 0) cnt = 0;
    __syncthreads();
    const float4* row = (const float4*)(C + (size_t)n * N_);
    for (int j4 = tid; j4 < N_ / 4; j4 += 256) {
        float4 v = row[j4];
        int base = j4 * 4;
        #pragma unroll
        for (int q = 0; q < 4; ++q) {
            float f = (q == 0) ? v.x : (q == 1) ? v.y : (q == 2) ? v.z : v.w;
            if (f != 0.0f) {
                uint32_t p = atomicAdd(&cnt, 1u);
                uint32_t m = (uint32_t)(base + q);
                if (p < DEG_SLOTS) nbr[n * DEG_SLOTS + p] = m * (uint32_t)B_;
            }
        }
    }
    __syncthreads();
    uint32_t c = min(cnt, (uint32_t)DEG_SLOTS);
    if (tid == 0) deg[n] = c;
    if (tid < DEG_SLOTS && (uint32_t)tid >= c)
        nbr[n * DEG_SLOTS + tid] = PAD_E;
}

// two-level grid barrier: 16 padded arrival counters; block 0 detects, sets flag.
// Release add emits buffer_wbl2 sc1 (flush dirty L2 to L3); acquire loads emit
// buffer_inv sc1 (drop stale local-L2 lines) -> plain loads/stores are coherent
// across phases.
__device__ __forceinline__ void gbar(uint32_t* bar, uint32_t phase) {
    __syncthreads();
    int tid = threadIdx.x;
    int bid = blockIdx.x;
    if (tid == 0)
        __hip_atomic_fetch_add(&bar[(bid & 15) * 32], 1u,
                               __ATOMIC_RELEASE, __HIP_MEMORY_SCOPE_AGENT);
    if (bid == 0) {
        if (tid < 16) {
            uint32_t tgt = (NBLK / 16) * phase;
            while (__hip_atomic_load(&bar[tid * 32], __ATOMIC_ACQUIRE,
                                     __HIP_MEMORY_SCOPE_AGENT) < tgt)
                __builtin_amdgcn_s_sleep(2);
        }
        __syncthreads();
        if (tid == 0)
            __hip_atomic_store(&bar[512], phase,
                               __ATOMIC_RELEASE, __HIP_MEMORY_SCOPE_AGENT);
    }
    if (tid == 0) {
        while (__hip_atomic_load(&bar[512], __ATOMIC_ACQUIRE,
                                 __HIP_MEMORY_SCOPE_AGENT) < phase)
            __builtin_amdgcn_s_sleep(2);
    }
    __syncthreads();
}

// Persistent kernel: all 10 steps. Block = 16 neurons x 256 batches (grid 1024 =
// 4 blocks/CU, co-resident via cooperative launch). Thread = 1 neuron x 16
// batches; v lives in 16 VGPRs for the whole simulation. Spikes as byte rows
// (round-10 format), uint4 gathers, LDS-broadcast neighbor entries.
__global__ __launch_bounds__(256, 4) void persist_k(const float* __restrict__ ext,
                                                    const float* __restrict__ memb,
                                                    const float* __restrict__ thr,
                                                    const uint32_t* __restrict__ r0nz,
                                                    uint32_t* __restrict__ colAny,
                                                    const uint32_t* __restrict__ deg,
                                                    const uint32_t* __restrict__ nbr,
                                                    unsigned char* __restrict__ sExp,
                                                    float* __restrict__ out,
                                                    uint32_t* bar) {
    __shared__ uint32_t s_nbr[16 * DEG_SLOTS];
    __shared__ float s_thr[16], s_mb[16];
    __shared__ uint32_t s_maxd;
    __shared__ float tile[16][257];      // ext transpose; later reused as byte tile for out

    int bid = blockIdx.x;
    int grp = bid >> 2, bc = bid & 3;    // bc in LOW bits -> XCD batch-slice affinity
    int n0 = grp * 16, b0 = bc * 256;
    int w = n0 >> 5;
    int tid = threadIdx.x;
    int wv = tid >> 6, lane = tid & 63;
    int g = lane >> 4;
    int nn = wv * 4 + g, n = n0 + nn;
    int bb_l = (lane & 15) * 16;
    int bb = b0 + bb_l;

    if (tid == 0) s_maxd = 0;
    for (int i = tid; i < 16 * DEG_SLOTS; i += 256) s_nbr[i] = nbr[n0 * DEG_SLOTS + i];
    __syncthreads();
    if (tid < 16) {
        uint32_t d = deg[n0 + tid];
        s_thr[tid] = thr[n0 + tid];
        s_mb[tid]  = memb[n0 + tid];
        atomicMax(&s_maxd, d);
    }
    #pragma unroll
    for (int p = 0; p < 4; ++p) {        // stage ext[b0..b0+255][n0..n0+15] transposed
        int i = tid + p * 256;
        int r = i >> 2, c4 = (i & 3) * 4;
        float4 e4 = *(const float4*)&ext[(size_t)(b0 + r) * N_ + n0 + c4];
        tile[c4 + 0][r] = e4.x;
        tile[c4 + 1][r] = e4.y;
        tile[c4 + 2][r] = e4.z;
        tile[c4 + 3][r] = e4.w;
    }
    __syncthreads();

    uint32_t maxd = s_maxd;
    float tn = s_thr[nn];
    const uint32_t* lst = &s_nbr[nn * DEG_SLOTS];

    float v[16];
    {
        float mb = s_mb[nn];
        #pragma unroll
        for (int i = 0; i < 16; ++i)
            v[i] = __fadd_rn(mb, tile[nn][bb_l + i]);
    }

    uint32_t spk[4];

    // ---- step 0: external input only ----
    {
        uint32_t blockedW = r0nz[w];                 // colAny rows 0,1 are zero
        uint32_t nb = ((blockedW >> (n & 31)) & 1u) ^ 1u;
        #pragma unroll
        for (int dw = 0; dw < 4; ++dw) {
            int sp0 = (v[dw * 4 + 0] > tn) && nb;
            int sp1 = (v[dw * 4 + 1] > tn) && nb;
            int sp2 = (v[dw * 4 + 2] > tn) && nb;
            int sp3 = (v[dw * 4 + 3] > tn) && nb;
            spk[dw] = (uint32_t)sp0 | ((uint32_t)sp1 << 8) |
                      ((uint32_t)sp2 << 16) | ((uint32_t)sp3 << 24);
            v[dw * 4 + 0] = __fmul_rn(sp0 ? 0.0f : v[dw * 4 + 0], 0.95f);
            v[dw * 4 + 1] = __fmul_rn(sp1 ? 0.0f : v[dw * 4 + 1], 0.95f);
            v[dw * 4 + 2] = __fmul_rn(sp2 ? 0.0f : v[dw * 4 + 2], 0.95f);
            v[dw * 4 + 3] = __fmul_rn(sp3 ? 0.0f : v[dw * 4 + 3], 0.95f);
        }
        *(uint4*)(sExp + (size_t)n * B_ + bb) = make_uint4(spk[0], spk[1], spk[2], spk[3]);
        int anyl = (spk[0] | spk[1] | spk[2] | spk[3]) != 0;
        unsigned long long m = __ballot(anyl);
        if (lane == 0) {
            uint32_t bits = 0;
            #pragma unroll
            for (int g2 = 0; g2 < 4; ++g2)
                if ((m >> (16 * g2)) & 0xFFFFull)
                    bits |= 1u << ((n0 + wv * 4 + g2) & 31);
            if (bits) atomicOr(&colAny[2 * W_ + w], bits);
        }
    }
    gbar(bar, 1);

    // ---- steps 1..9 ----
    unsigned char* sprev = sExp;
    unsigned char* snext = sExp + (size_t)SEXP_BUF;
    for (int s = 1; s < NSTEPS_; ++s) {
        uint32_t blockedW = colAny[(s + 1) * W_ + w] | colAny[s * W_ + w] | r0nz[s * W_ + w];
        uint32_t nb = ((blockedW >> (n & 31)) & 1u) ^ 1u;
        uint32_t a0 = 0, a1 = 0, a2 = 0, a3 = 0;
        #pragma unroll
        for (int j = 0; j < UNR; ++j) {
            uint32_t e = lst[j];                     // LDS broadcast within 16-lane group
            uint4 d4 = *(const uint4*)(sprev + e + bb);
            a0 += d4.x; a1 += d4.y; a2 += d4.z; a3 += d4.w;
        }
        if (maxd > UNR) {                            // block-uniform tail; sentinels -> zero row
            for (uint32_t j = UNR; j < maxd; ++j) {
                uint32_t e = lst[j];
                uint4 d4 = *(const uint4*)(sprev + e + bb);
                a0 += d4.x; a1 += d4.y; a2 += d4.z; a3 += d4.w;
            }
        }
        uint32_t accs[4] = {a0, a1, a2, a3};
        #pragma unroll
        for (int dw = 0; dw < 4; ++dw) {
            uint32_t acc = accs[dw];
            float v0 = __fadd_rn(v[dw * 4 + 0], __fmul_rn(0.1f, (float)( acc        & 255u)));
            float v1 = __fadd_rn(v[dw * 4 + 1], __fmul_rn(0.1f, (float)((acc >>  8) & 255u)));
            float v2 = __fadd_rn(v[dw * 4 + 2], __fmul_rn(0.1f, (float)((acc >> 16) & 255u)));
            float v3 = __fadd_rn(v[dw * 4 + 3], __fmul_rn(0.1f, (float)( acc >> 24        )));
            int sp0 = (v0 > tn) && nb;
            int sp1 = (v1 > tn) && nb;
            int sp2 = (v2 > tn) && nb;
            int sp3 = (v3 > tn) && nb;
            spk[dw] = (uint32_t)sp0 | ((uint32_t)sp1 << 8) |
                      ((uint32_t)sp2 << 16) | ((uint32_t)sp3 << 24);
            if (s < NSTEPS_ - 1) {
                v[dw * 4 + 0] = __fmul_rn(sp0 ? 0.0f : v0, 0.95f);
                v[dw * 4 + 1] = __fmul_rn(sp1 ? 0.0f : v1, 0.95f);
                v[dw * 4 + 2] = __fmul_rn(sp2 ? 0.0f : v2, 0.95f);
                v[dw * 4 + 3] = __fmul_rn(sp3 ? 0.0f : v3, 0.95f);
            }
        }
        if (s < NSTEPS_ - 1) {
            *(uint4*)(snext + (size_t)n * B_ + bb) =
                make_uint4(spk[0], spk[1], spk[2], spk[3]);
            int anyl = (spk[0] | spk[1] | spk[2] | spk[3]) != 0;
            unsigned long long m = __ballot(anyl);
            if (lane == 0) {
                uint32_t bits = 0;
                #pragma unroll
                for (int g2 = 0; g2 < 4; ++g2)
                    if ((m >> (16 * g2)) & 0xFFFFull)
                        bits |= 1u << ((n0 + wv * 4 + g2) & 31);
                if (bits) atomicOr(&colAny[(s + 2) * W_ + w], bits);
            }
            gbar(bar, (uint32_t)(s + 1));
        }
        unsigned char* t = sprev; sprev = snext; snext = t;
    }

    // ---- output: step-9 spikes (in regs) -> byte tile -> [b][n] float4 ----
    unsigned char* bt = (unsigned char*)&tile[0][0];   // [16][256] bytes
    __syncthreads();
    *(uint4*)&bt[nn * 256 + bb_l] = make_uint4(spk[0], spk[1], spk[2], spk[3]);
    __syncthreads();
    #pragma unroll
    for (int p = 0; p < 4; ++p) {
        int i = tid + p * 256;
        int r = i >> 2, c4 = (i & 3) * 4;
        float4 o;
        o.x = (float)bt[(c4 + 0) * 256 + r];
        o.y = (float)bt[(c4 + 1) * 256 + r];
        o.z = (float)bt[(c4 + 2) * 256 + r];
        o.w = (float)bt[(c4 + 3) * 256 + r];
        *(float4*)&out[(size_t)(b0 + r) * N_ + n0 + c4] = o;
    }
}

extern "C" void kernel_launch(void* const* d_in, const int* in_sizes, int n_in,
                              void* d_out, int out_size, void* d_ws, size_t ws_size,
                              hipStream_t stream) {
    const float* ext     = (const float*)d_in[0];
    const float* C       = (const float*)d_in[1];
    const float* memb    = (const float*)d_in[2];
    const float* thr     = (const float*)d_in[3];
    const float* refr_in = (const float*)d_in[4];

    char* ws = (char*)d_ws;
    uint32_t* r0nz   = (uint32_t*)(ws + OFF_R0NZ);
    uint32_t* colAny = (uint32_t*)(ws + OFF_COLANY);
    uint32_t* bar    = (uint32_t*)(ws + OFF_BAR);
    uint32_t* deg    = (uint32_t*)(ws + OFF_DEG);
    uint32_t* nbr    = (uint32_t*)(ws + OFF_NBR);
    unsigned char* sExp = (unsigned char*)(ws + OFF_SEXP);
    float*    out    = (float*)d_out;

    build_k<<<dim3(N_), dim3(256), 0, stream>>>(
        C, refr_in, deg, nbr, r0nz, colAny, bar,
        (uint32_t*)(sExp + (size_t)N_ * B_),
        (uint32_t*)(sExp + (size_t)SEXP_BUF + (size_t)N_ * B_));

    void* args[] = {(void*)&ext, (void*)&memb, (void*)&thr, (void*)&r0nz,
                    (void*)&colAny, (void*)&deg, (void*)&nbr, (void*)&sExp,
                    (void*)&out, (void*)&bar};
    hipLaunchCooperativeKernel((const void*)persist_k, dim3(NBLK), dim3(256),
                               args, 0, stream);
}

// Round 12
// 190.581 us; speedup vs baseline: 3.9881x; 3.9881x over previous
//
#include <hip/hip_runtime.h>
#include <stdint.h>

#define N_ 4096
#define B_ 1024
#define W_ 128          // N/32 neuron-words (colAny bitmasks)
#define NSTEPS_ 10
#define DEG_SLOTS 40    // padded neighbor-list slots (deg ~ Poisson(12); P(>40) ~ 1e-11)
#define UNR 16          // static unrolled gather depth (sentinel-padded)
#define PAD_E ((uint32_t)(N_ * B_))   // sentinel -> byte offset of zero pad row
#define NBLK 1024

// ws layout (bytes):
//   r0nz   : 0      .. 5120      u32[NSTEPS][W]    bit n: pure-decay refr!=0 before step s
//   colAny : 5120   .. 11264     u32[NSTEPS+2][W]  rows 0,1 zero; step s ORs row s+2
//   bar    : 11264  .. 13568     u32[576]: 16 arrival ctrs at stride 32 (128B) + flag at [512]
//   deg    : 13568  .. 29952     u32[N]
//   nbr    : 29952  .. 685312    u32[N][DEG_SLOTS] entry = m*B (byte offset); sentinel N*B
//   sExp   : 685312 .. ~9.08MB   u8[2][(N+1)*B]    spike BYTES [n][b]; row N_ always zero
#define OFF_R0NZ   0
#define OFF_COLANY 5120
#define OFF_BAR    11264
#define OFF_DEG    13568
#define OFF_NBR    29952
#define OFF_SEXP   685312
#define SEXP_BUF   ((N_ + 1) * B_)

// build_k: neighbor lists from C; blocks 0..15 additionally do all one-time init.
__global__ __launch_bounds__(256) void build_k(const float* __restrict__ C,
                                               const float* __restrict__ refr_in,
                                               uint32_t* __restrict__ deg,
                                               uint32_t* __restrict__ nbr,
                                               uint32_t* __restrict__ r0nz,
                                               uint32_t* __restrict__ colAny,
                                               uint32_t* __restrict__ bar,
                                               uint32_t* __restrict__ pad0,
                                               uint32_t* __restrict__ pad1) {
    __shared__ uint32_t cnt;
    int tid = threadIdx.x;
    if (blockIdx.x < 16) {
        int i = blockIdx.x * 256 + tid;
        if (i < (NSTEPS_ + 2) * W_) {
            colAny[i] = 0u;
        } else if (i >= 1536 && i < 2112) {
            bar[i - 1536] = 0u;              // barrier counters + flag
        } else if (i >= 2112 && i < 2112 + W_) {
            int w = i - 2112;
            uint32_t bits[NSTEPS_];
            #pragma unroll
            for (int s = 0; s < NSTEPS_; ++s) bits[s] = 0u;
            for (int k = 0; k < 32; ++k) {
                float r = refr_in[w * 32 + k];
                #pragma unroll
                for (int s = 0; s < NSTEPS_; ++s) {
                    bits[s] |= (r != 0.0f ? 1u : 0u) << k;
                    r = fminf(fmaxf(r - 1.0f, 0.0f), 10.0f);
                }
            }
            #pragma unroll
            for (int s = 0; s < NSTEPS_; ++s) r0nz[s * W_ + w] = bits[s];
        } else if (i >= 2560 && i < 2816) {
            pad0[i - 2560] = 0u;             // zero pad row of sExp buf0
        } else if (i >= 2816 && i < 3072) {
            pad1[i - 2816] = 0u;             // zero pad row of sExp buf1
        }
    }
    int n = blockIdx.x;
    if (tid == 0) cnt = 0;
    __syncthreads();
    const float4* row = (const float4*)(C + (size_t)n * N_);
    for (int j4 = tid; j4 < N_ / 4; j4 += 256) {
        float4 v = row[j4];
        int base = j4 * 4;
        #pragma unroll
        for (int q = 0; q < 4; ++q) {
            float f = (q == 0) ? v.x : (q == 1) ? v.y : (q == 2) ? v.z : v.w;
            if (f != 0.0f) {
                uint32_t p = atomicAdd(&cnt, 1u);
                uint32_t m = (uint32_t)(base + q);
                if (p < DEG_SLOTS) nbr[n * DEG_SLOTS + p] = m * (uint32_t)B_;
            }
        }
    }
    __syncthreads();
    uint32_t c = min(cnt, (uint32_t)DEG_SLOTS);
    if (tid == 0) deg[n] = c;
    if (tid < DEG_SLOTS && (uint32_t)tid >= c)
        nbr[n * DEG_SLOTS + tid] = PAD_E;
}

// Grid barrier with NO L2 flush/inv in the spin path: relaxed L3-homed atomics
// for arrivals + flag; exactly ONE acquire load (one buffer_inv) per block per
// phase, executed after the flag is seen, so the following plain gather loads
// read fresh data. __syncthreads() before arrival drains each wave's stores
// (compiler emits s_waitcnt vmcnt(0) before s_barrier).
__device__ __forceinline__ void gbar(uint32_t* bar, uint32_t phase) {
    __syncthreads();                         // all waves' atomic stores acked
    int tid = threadIdx.x, bid = blockIdx.x;
    if (tid == 0)
        __hip_atomic_fetch_add(&bar[(bid & 15) * 32], 1u,
                               __ATOMIC_RELAXED, __HIP_MEMORY_SCOPE_AGENT);
    if (bid == 0) {
        if (tid < 16) {
            uint32_t tgt = (NBLK / 16) * phase;
            while (__hip_atomic_load(&bar[tid * 32], __ATOMIC_RELAXED,
                                     __HIP_MEMORY_SCOPE_AGENT) < tgt)
                __builtin_amdgcn_s_sleep(2);
        }
        __syncthreads();
        if (tid == 0)
            __hip_atomic_store(&bar[512], phase,
                               __ATOMIC_RELAXED, __HIP_MEMORY_SCOPE_AGENT);
    }
    if (tid == 0) {
        while (__hip_atomic_load(&bar[512], __ATOMIC_RELAXED,
                                 __HIP_MEMORY_SCOPE_AGENT) < phase)
            __builtin_amdgcn_s_sleep(2);
        (void)__hip_atomic_load(&bar[512], __ATOMIC_ACQUIRE,     // one buffer_inv
                                __HIP_MEMORY_SCOPE_AGENT);
    }
    __syncthreads();
}

// Persistent kernel: all 10 steps. Block = 16 neurons x 256 batches (grid 1024 =
// 4 blocks/CU, cooperative). Thread = 1 neuron x 16 batches; v lives in 16 VGPRs.
// Spike bytes written via relaxed agent-scope b64 atomic stores (L3 write-through,
// no dirty L2); gathers are PLAIN uint4 loads (L2-cached within a step, made
// fresh by the barrier's single acquire-inv).
__global__ __launch_bounds__(256, 4) void persist_k(const float* __restrict__ ext,
                                                    const float* __restrict__ memb,
                                                    const float* __restrict__ thr,
                                                    const uint32_t* __restrict__ r0nz,
                                                    uint32_t* __restrict__ colAny,
                                                    const uint32_t* __restrict__ deg,
                                                    const uint32_t* __restrict__ nbr,
                                                    unsigned char* __restrict__ sExp,
                                                    float* __restrict__ out,
                                                    uint32_t* bar) {
    __shared__ uint32_t s_nbr[16 * DEG_SLOTS];
    __shared__ float s_thr[16], s_mb[16];
    __shared__ uint32_t s_maxd;
    __shared__ float tile[16][257];      // ext transpose; later reused as byte tile for out

    int bid = blockIdx.x;
    int grp = bid >> 2, bc = bid & 3;    // bc in LOW bits -> XCD batch-slice affinity
    int n0 = grp * 16, b0 = bc * 256;
    int w = n0 >> 5;
    int tid = threadIdx.x;
    int wv = tid >> 6, lane = tid & 63;
    int g = lane >> 4;
    int nn = wv * 4 + g, n = n0 + nn;
    int bb_l = (lane & 15) * 16;
    int bb = b0 + bb_l;

    if (tid == 0) s_maxd = 0;
    for (int i = tid; i < 16 * DEG_SLOTS; i += 256) s_nbr[i] = nbr[n0 * DEG_SLOTS + i];
    __syncthreads();
    if (tid < 16) {
        uint32_t d = deg[n0 + tid];
        s_thr[tid] = thr[n0 + tid];
        s_mb[tid]  = memb[n0 + tid];
        atomicMax(&s_maxd, d);
    }
    #pragma unroll
    for (int p = 0; p < 4; ++p) {        // stage ext[b0..b0+255][n0..n0+15] transposed
        int i = tid + p * 256;
        int r = i >> 2, c4 = (i & 3) * 4;
        float4 e4 = *(const float4*)&ext[(size_t)(b0 + r) * N_ + n0 + c4];
        tile[c4 + 0][r] = e4.x;
        tile[c4 + 1][r] = e4.y;
        tile[c4 + 2][r] = e4.z;
        tile[c4 + 3][r] = e4.w;
    }
    __syncthreads();

    uint32_t maxd = s_maxd;
    float tn = s_thr[nn];
    const uint32_t* lst = &s_nbr[nn * DEG_SLOTS];

    float v[16];
    {
        float mb = s_mb[nn];
        #pragma unroll
        for (int i = 0; i < 16; ++i)
            v[i] = __fadd_rn(mb, tile[nn][bb_l + i]);
    }

    uint32_t spk[4];

    // ---- step 0: external input only ----
    {
        uint32_t blockedW = r0nz[w];                 // colAny rows 0,1 are zero
        uint32_t nb = ((blockedW >> (n & 31)) & 1u) ^ 1u;
        #pragma unroll
        for (int dw = 0; dw < 4; ++dw) {
            int sp0 = (v[dw * 4 + 0] > tn) && nb;
            int sp1 = (v[dw * 4 + 1] > tn) && nb;
            int sp2 = (v[dw * 4 + 2] > tn) && nb;
            int sp3 = (v[dw * 4 + 3] > tn) && nb;
            spk[dw] = (uint32_t)sp0 | ((uint32_t)sp1 << 8) |
                      ((uint32_t)sp2 << 16) | ((uint32_t)sp3 << 24);
            v[dw * 4 + 0] = __fmul_rn(sp0 ? 0.0f : v[dw * 4 + 0], 0.95f);
            v[dw * 4 + 1] = __fmul_rn(sp1 ? 0.0f : v[dw * 4 + 1], 0.95f);
            v[dw * 4 + 2] = __fmul_rn(sp2 ? 0.0f : v[dw * 4 + 2], 0.95f);
            v[dw * 4 + 3] = __fmul_rn(sp3 ? 0.0f : v[dw * 4 + 3], 0.95f);
        }
        unsigned long long p0 = (unsigned long long)spk[0] | ((unsigned long long)spk[1] << 32);
        unsigned long long p1 = (unsigned long long)spk[2] | ((unsigned long long)spk[3] << 32);
        unsigned long long* dst = (unsigned long long*)(sExp + (size_t)n * B_ + bb);
        __hip_atomic_store(dst,     p0, __ATOMIC_RELAXED, __HIP_MEMORY_SCOPE_AGENT);
        __hip_atomic_store(dst + 1, p1, __ATOMIC_RELAXED, __HIP_MEMORY_SCOPE_AGENT);
        int anyl = (spk[0] | spk[1] | spk[2] | spk[3]) != 0;
        unsigned long long m = __ballot(anyl);
        if (lane == 0) {
            uint32_t bits = 0;
            #pragma unroll
            for (int g2 = 0; g2 < 4; ++g2)
                if ((m >> (16 * g2)) & 0xFFFFull)
                    bits |= 1u << ((n0 + wv * 4 + g2) & 31);
            if (bits) atomicOr(&colAny[2 * W_ + w], bits);
        }
    }
    gbar(bar, 1);

    // ---- steps 1..9 ----
    unsigned char* sprev = sExp;
    unsigned char* snext = sExp + (size_t)SEXP_BUF;
    for (int s = 1; s < NSTEPS_; ++s) {
        uint32_t blockedW = colAny[(s + 1) * W_ + w] | colAny[s * W_ + w] | r0nz[s * W_ + w];
        uint32_t nb = ((blockedW >> (n & 31)) & 1u) ^ 1u;
        uint32_t a0 = 0, a1 = 0, a2 = 0, a3 = 0;
        #pragma unroll
        for (int j = 0; j < UNR; ++j) {
            uint32_t e = lst[j];                     // LDS broadcast within 16-lane group
            uint4 d4 = *(const uint4*)(sprev + e + bb);
            a0 += d4.x; a1 += d4.y; a2 += d4.z; a3 += d4.w;
        }
        if (maxd > UNR) {                            // block-uniform tail; sentinels -> zero row
            for (uint32_t j = UNR; j < maxd; ++j) {
                uint32_t e = lst[j];
                uint4 d4 = *(const uint4*)(sprev + e + bb);
                a0 += d4.x; a1 += d4.y; a2 += d4.z; a3 += d4.w;
            }
        }
        uint32_t accs[4] = {a0, a1, a2, a3};
        #pragma unroll
        for (int dw = 0; dw < 4; ++dw) {
            uint32_t acc = accs[dw];
            float v0 = __fadd_rn(v[dw * 4 + 0], __fmul_rn(0.1f, (float)( acc        & 255u)));
            float v1 = __fadd_rn(v[dw * 4 + 1], __fmul_rn(0.1f, (float)((acc >>  8) & 255u)));
            float v2 = __fadd_rn(v[dw * 4 + 2], __fmul_rn(0.1f, (float)((acc >> 16) & 255u)));
            float v3 = __fadd_rn(v[dw * 4 + 3], __fmul_rn(0.1f, (float)( acc >> 24        )));
            int sp0 = (v0 > tn) && nb;
            int sp1 = (v1 > tn) && nb;
            int sp2 = (v2 > tn) && nb;
            int sp3 = (v3 > tn) && nb;
            spk[dw] = (uint32_t)sp0 | ((uint32_t)sp1 << 8) |
                      ((uint32_t)sp2 << 16) | ((uint32_t)sp3 << 24);
            if (s < NSTEPS_ - 1) {
                v[dw * 4 + 0] = __fmul_rn(sp0 ? 0.0f : v0, 0.95f);
                v[dw * 4 + 1] = __fmul_rn(sp1 ? 0.0f : v1, 0.95f);
                v[dw * 4 + 2] = __fmul_rn(sp2 ? 0.0f : v2, 0.95f);
                v[dw * 4 + 3] = __fmul_rn(sp3 ? 0.0f : v3, 0.95f);
            }
        }
        if (s < NSTEPS_ - 1) {
            unsigned long long p0 = (unsigned long long)spk[0] | ((unsigned long long)spk[1] << 32);
            unsigned long long p1 = (unsigned long long)spk[2] | ((unsigned long long)spk[3] << 32);
            unsigned long long* dst = (unsigned long long*)(snext + (size_t)n * B_ + bb);
            __hip_atomic_store(dst,     p0, __ATOMIC_RELAXED, __HIP_MEMORY_SCOPE_AGENT);
            __hip_atomic_store(dst + 1, p1, __ATOMIC_RELAXED, __HIP_MEMORY_SCOPE_AGENT);
            int anyl = (spk[0] | spk[1] | spk[2] | spk[3]) != 0;
            unsigned long long m = __ballot(anyl);
            if (lane == 0) {
                uint32_t bits = 0;
                #pragma unroll
                for (int g2 = 0; g2 < 4; ++g2)
                    if ((m >> (16 * g2)) & 0xFFFFull)
                        bits |= 1u << ((n0 + wv * 4 + g2) & 31);
                if (bits) atomicOr(&colAny[(s + 2) * W_ + w], bits);
            }
            gbar(bar, (uint32_t)(s + 1));
        }
        unsigned char* t = sprev; sprev = snext; snext = t;
    }

    // ---- output: step-9 spikes (in regs) -> byte tile -> [b][n] float4 ----
    unsigned char* bt = (unsigned char*)&tile[0][0];   // [16][256] bytes
    __syncthreads();
    *(uint4*)&bt[nn * 256 + bb_l] = make_uint4(spk[0], spk[1], spk[2], spk[3]);
    __syncthreads();
    #pragma unroll
    for (int p = 0; p < 4; ++p) {
        int i = tid + p * 256;
        int r = i >> 2, c4 = (i & 3) * 4;
        float4 o;
        o.x = (float)bt[(c4 + 0) * 256 + r];
        o.y = (float)bt[(c4 + 1) * 256 + r];
        o.z = (float)bt[(c4 + 2) * 256 + r];
        o.w = (float)bt[(c4 + 3) * 256 + r];
        *(float4*)&out[(size_t)(b0 + r) * N_ + n0 + c4] = o;
    }
}

extern "C" void kernel_launch(void* const* d_in, const int* in_sizes, int n_in,
                              void* d_out, int out_size, void* d_ws, size_t ws_size,
                              hipStream_t stream) {
    const float* ext     = (const float*)d_in[0];
    const float* C       = (const float*)d_in[1];
    const float* memb    = (const float*)d_in[2];
    const float* thr     = (const float*)d_in[3];
    const float* refr_in = (const float*)d_in[4];

    char* ws = (char*)d_ws;
    uint32_t* r0nz   = (uint32_t*)(ws + OFF_R0NZ);
    uint32_t* colAny = (uint32_t*)(ws + OFF_COLANY);
    uint32_t* bar    = (uint32_t*)(ws + OFF_BAR);
    uint32_t* deg    = (uint32_t*)(ws + OFF_DEG);
    uint32_t* nbr    = (uint32_t*)(ws + OFF_NBR);
    unsigned char* sExp = (unsigned char*)(ws + OFF_SEXP);
    float*    out    = (float*)d_out;

    build_k<<<dim3(N_), dim3(256), 0, stream>>>(
        C, refr_in, deg, nbr, r0nz, colAny, bar,
        (uint32_t*)(sExp + (size_t)N_ * B_),
        (uint32_t*)(sExp + (size_t)SEXP_BUF + (size_t)N_ * B_));

    void* args[] = {(void*)&ext, (void*)&memb, (void*)&thr, (void*)&r0nz,
                    (void*)&colAny, (void*)&deg, (void*)&nbr, (void*)&sExp,
                    (void*)&out, (void*)&bar};
    hipLaunchCooperativeKernel((const void*)persist_k, dim3(NBLK), dim3(256),
                               args, 0, stream);
}

// Round 15
// 169.023 us; speedup vs baseline: 4.4968x; 1.1275x over previous
//
#include <hip/hip_runtime.h>
#include <stdint.h>

#define N_ 4096
#define B_ 1024
#define W_ 128          // N/32 neuron-words (colAny bitmasks)
#define NSTEPS_ 10
#define DEG_SLOTS 40    // padded neighbor-list slots (deg ~ Poisson(12); P(>40) ~ 1e-11)
#define UNR 16          // static unrolled gather depth (sentinel-padded)
#define PAD_E ((uint32_t)(N_ * B_))   // sentinel -> byte offset of zero pad row

// ws layout (bytes):
//   r0nz   : 0       .. 5120      u32[NSTEPS][W]   bit n: pure-decay refr!=0 before step s
//   colAny : 5120    .. 11264     u32[NSTEPS+2][W] rows 0,1 zero; step s ORs row s+2
//   deg    : 11264   .. 27648     u32[N]
//   nbr    : 27648   .. 683008    u32[N][DEG_SLOTS] entry = m*B (byte off); sentinel N*B
//   sExp   : 683008  .. 9073664   u8[2][(N+1)*B]   spike BYTES [n][b]; row N_ always zero
//   vt     : 9073664 .. 25850880  f32[N][B]        v state (ws is ~268 MB)
#define OFF_R0NZ   0
#define OFF_COLANY 5120
#define OFF_DEG    11264
#define OFF_NBR    27648
#define OFF_SEXP   683008
#define OFF_VT     9073664
#define SEXP_BUF   ((N_ + 1) * B_)

// build_k: neighbor lists from C; blocks 0..15 additionally do all one-time init.
__global__ __launch_bounds__(256) void build_k(const float* __restrict__ C,
                                               const float* __restrict__ refr_in,
                                               uint32_t* __restrict__ deg,
                                               uint32_t* __restrict__ nbr,
                                               uint32_t* __restrict__ r0nz,
                                               uint32_t* __restrict__ colAny,
                                               uint32_t* __restrict__ pad0,
                                               uint32_t* __restrict__ pad1) {
    __shared__ uint32_t cnt;
    int tid = threadIdx.x;
    if (blockIdx.x < 16) {
        int i = blockIdx.x * 256 + tid;
        if (i < (NSTEPS_ + 2) * W_) {
            colAny[i] = 0u;
        } else if (i >= 2048 && i < 2048 + W_) {
            int w = i - 2048;
            uint32_t bits[NSTEPS_];
            #pragma unroll
            for (int s = 0; s < NSTEPS_; ++s) bits[s] = 0u;
            for (int k = 0; k < 32; ++k) {
                float r = refr_in[w * 32 + k];
                #pragma unroll
                for (int s = 0; s < NSTEPS_; ++s) {
                    bits[s] |= (r != 0.0f ? 1u : 0u) << k;
                    r = fminf(fmaxf(r - 1.0f, 0.0f), 10.0f);
                }
            }
            #pragma unroll
            for (int s = 0; s < NSTEPS_; ++s) r0nz[s * W_ + w] = bits[s];
        } else if (i >= 3072 && i < 3072 + 256) {
            pad0[i - 3072] = 0u;          // zero pad row of sExp buf0 (1 KB)
        } else if (i >= 3328 && i < 3328 + 256) {
            pad1[i - 3328] = 0u;          // zero pad row of sExp buf1
        }
    }
    int n = blockIdx.x;
    if (tid == 0) cnt = 0;
    __syncthreads();
    const float4* row = (const float4*)(C + (size_t)n * N_);
    for (int j4 = tid; j4 < N_ / 4; j4 += 256) {
        float4 v = row[j4];
        int base = j4 * 4;
        #pragma unroll
        for (int q = 0; q < 4; ++q) {
            float f = (q == 0) ? v.x : (q == 1) ? v.y : (q == 2) ? v.z : v.w;
            if (f != 0.0f) {
                uint32_t p = atomicAdd(&cnt, 1u);
                uint32_t m = (uint32_t)(base + q);
                if (p < DEG_SLOTS) nbr[n * DEG_SLOTS + p] = m * (uint32_t)B_;
            }
        }
    }
    __syncthreads();
    uint32_t c = min(cnt, (uint32_t)DEG_SLOTS);
    if (tid == 0) deg[n] = c;
    if (tid < DEG_SLOTS && (uint32_t)tid >= c)
        nbr[n * DEG_SLOTS + tid] = PAD_E;
}

// step 0: v = memb + ext (float4 loads + LDS transpose), threshold, spike bytes
__global__ __launch_bounds__(256, 4) void first_k(const float* __restrict__ ext,
                                                  const float* __restrict__ memb,
                                                  const float* __restrict__ thr,
                                                  const uint32_t* __restrict__ r0nz0,
                                                  float* __restrict__ vt,
                                                  unsigned char* __restrict__ snext,
                                                  uint32_t* __restrict__ colAnyW) {
    __shared__ float tile[32][65];
    __shared__ float s_thr[32], s_mb[32];
    int w = blockIdx.x & (W_ - 1);
    int b0 = (blockIdx.x >> 7) * 64;
    int n0 = w * 32;
    int tid = threadIdx.x;
    if (tid < 32) { s_thr[tid] = thr[n0 + tid]; s_mb[tid] = memb[n0 + tid]; }
    #pragma unroll
    for (int p = 0; p < 2; ++p) {
        int r  = (tid >> 3) + p * 32;     // batch row 0..63
        int c4 = (tid & 7) * 4;           // neuron col (float4)
        float4 e4 = *(const float4*)&ext[(size_t)(b0 + r) * N_ + n0 + c4];
        tile[c4 + 0][r] = e4.x;
        tile[c4 + 1][r] = e4.y;
        tile[c4 + 2][r] = e4.z;
        tile[c4 + 3][r] = e4.w;
    }
    __syncthreads();
    int wv = tid >> 6, b_l = tid & 63, b = b0 + b_l;
    uint32_t blocked = r0nz0[w];
    uint32_t anyMask = 0;
    #pragma unroll
    for (int k = 0; k < 8; ++k) {
        int nn = wv * 8 + k, n = n0 + nn;
        float v = __fadd_rn(s_mb[nn], tile[nn][b_l]);
        int sp = (v > s_thr[nn]) && !((blocked >> nn) & 1u);
        v = sp ? 0.0f : v;
        v = __fmul_rn(v, 0.95f);
        vt[(size_t)n * B_ + b] = v;
        snext[(size_t)n * B_ + b] = (unsigned char)sp;
        if (__ballot(sp)) anyMask |= 1u << nn;
    }
    if (b_l == 0 && anyMask) atomicOr(&colAnyW[w], anyMask);
}

// block = 16 neurons x 256 batches; wave = 4 neurons x 256 b; lane = 1 neuron x
// 16 batches (uint4 gather loads). Batch chunk in LOW blockIdx bits -> each XCD
// owns one 256-batch slice (1 MB gather footprint, L2-resident). Grid 1024.
// LAST: fused output — spikes transposed via LDS byte tile, written to d_out as
// coalesced float4 rows; spike-byte store / colAny / vt store all skipped.
template <int LAST>
__global__ __launch_bounds__(256, 4) void step_k(const float* __restrict__ thr,
                                                 const uint32_t* __restrict__ deg,
                                                 const uint32_t* __restrict__ nbr,
                                                 const unsigned char* __restrict__ sprev,
                                                 unsigned char* __restrict__ snext,
                                                 float* __restrict__ vt,
                                                 const uint32_t* __restrict__ cA_a,
                                                 const uint32_t* __restrict__ cA_b,
                                                 const uint32_t* __restrict__ r0nzRow,
                                                 uint32_t* __restrict__ colAnyW,
                                                 float* __restrict__ out) {
    __shared__ uint32_t s_nbr[16 * DEG_SLOTS];
    __shared__ uint32_t s_deg[16];
    __shared__ float s_thr[16];
    __shared__ uint32_t s_maxd;
    __shared__ unsigned char s_out[16][256];   // LAST only: byte transpose tile
    int grp = blockIdx.x >> 2;           // 16-neuron group 0..255
    int bc  = blockIdx.x & 3;            // batch chunk 0..3 (low bits -> XCD affinity)
    int n0 = grp * 16, b0 = bc * 256;
    int w = n0 >> 5;                     // colAny word
    int tid = threadIdx.x;
    if (tid == 0) s_maxd = 0;
    for (int i = tid; i < 16 * DEG_SLOTS; i += 256) s_nbr[i] = nbr[n0 * DEG_SLOTS + i];
    __syncthreads();
    if (tid < 16) {
        uint32_t d = deg[n0 + tid];
        s_deg[tid] = d; s_thr[tid] = thr[n0 + tid];
        atomicMax(&s_maxd, d);
    }
    __syncthreads();
    uint32_t blockedW = cA_a[w] | cA_b[w] | r0nzRow[w];
    uint32_t maxd = s_maxd;
    int wv = tid >> 6, lane = tid & 63;
    int g = lane >> 4;                   // neuron sub-index in wave
    int nn = wv * 4 + g;                 // local neuron 0..15
    int n = n0 + nn;
    int bb_l = (lane & 15) * 16;
    int bb = b0 + bb_l;                  // 16 adjacent batches
    const uint32_t* lst = &s_nbr[nn * DEG_SLOTS];
    uint32_t a0 = 0, a1 = 0, a2 = 0, a3 = 0;   // packed byte accum, 16 cells
    #pragma unroll
    for (int j = 0; j < UNR; ++j) {
        uint32_t e = lst[j];             // LDS broadcast within 16-lane group
        uint4 d4 = *(const uint4*)(sprev + e + bb);
        a0 += d4.x; a1 += d4.y; a2 += d4.z; a3 += d4.w;
    }
    if (maxd > UNR) {                    // block-uniform tail; sentinels read zero row
        for (uint32_t j = UNR; j < maxd; ++j) {
            uint32_t e = lst[j];
            uint4 d4 = *(const uint4*)(sprev + e + bb);
            a0 += d4.x; a1 += d4.y; a2 += d4.z; a3 += d4.w;
        }
    }
    float tn = s_thr[nn];
    uint32_t nb = ((blockedW >> (n & 31)) & 1u) ^ 1u;
    const float4* vp = (const float4*)&vt[(size_t)n * B_ + bb];
    float4* vs = (float4*)&vt[(size_t)n * B_ + bb];
    uint32_t spk[4];
    uint32_t accs[4] = {a0, a1, a2, a3};
    #pragma unroll
    for (int dw = 0; dw < 4; ++dw) {
        uint32_t acc = accs[dw];
        float4 vv = vp[dw];
        float v0 = __fadd_rn(vv.x, __fmul_rn(0.1f, (float)( acc        & 255u)));
        float v1 = __fadd_rn(vv.y, __fmul_rn(0.1f, (float)((acc >>  8) & 255u)));
        float v2 = __fadd_rn(vv.z, __fmul_rn(0.1f, (float)((acc >> 16) & 255u)));
        float v3 = __fadd_rn(vv.w, __fmul_rn(0.1f, (float)( acc >> 24        )));
        int sp0 = (v0 > tn) && nb;
        int sp1 = (v1 > tn) && nb;
        int sp2 = (v2 > tn) && nb;
        int sp3 = (v3 > tn) && nb;
        spk[dw] = (uint32_t)sp0 | ((uint32_t)sp1 << 8) |
                  ((uint32_t)sp2 << 16) | ((uint32_t)sp3 << 24);
        if (!LAST) {
            v0 = __fmul_rn(sp0 ? 0.0f : v0, 0.95f);
            v1 = __fmul_rn(sp1 ? 0.0f : v1, 0.95f);
            v2 = __fmul_rn(sp2 ? 0.0f : v2, 0.95f);
            v3 = __fmul_rn(sp3 ? 0.0f : v3, 0.95f);
            vs[dw] = make_float4(v0, v1, v2, v3);
        }
    }
    if (!LAST) {
        *(uint4*)(snext + (size_t)n * B_ + bb) =
            make_uint4(spk[0], spk[1], spk[2], spk[3]);
        int anyl = (spk[0] | spk[1] | spk[2] | spk[3]) != 0u;
        unsigned long long m = __ballot(anyl);
        if (lane == 0) {
            uint32_t bits = 0;
            #pragma unroll
            for (int g2 = 0; g2 < 4; ++g2)
                if ((m >> (16 * g2)) & 0xFFFFull)
                    bits |= 1u << ((n0 + wv * 4 + g2) & 31);
            if (bits) atomicOr(&colAnyW[w], bits);
        }
    } else {
        // fused output: spikes -> LDS byte tile -> [b][n] float4 rows
        __syncthreads();
        *(uint4*)&s_out[nn][bb_l] = make_uint4(spk[0], spk[1], spk[2], spk[3]);
        __syncthreads();
        #pragma unroll
        for (int p = 0; p < 4; ++p) {
            int i = tid + p * 256;       // 1024 float4s: 256 batch rows x 4 cols
            int r = i >> 2, c4 = (i & 3) * 4;
            float4 o;
            o.x = (float)s_out[c4 + 0][r];
            o.y = (float)s_out[c4 + 1][r];
            o.z = (float)s_out[c4 + 2][r];
            o.w = (float)s_out[c4 + 3][r];
            *(float4*)&out[(size_t)(b0 + r) * N_ + n0 + c4] = o;
        }
    }
}

extern "C" void kernel_launch(void* const* d_in, const int* in_sizes, int n_in,
                              void* d_out, int out_size, void* d_ws, size_t ws_size,
                              hipStream_t stream) {
    const float* ext     = (const float*)d_in[0];
    const float* C       = (const float*)d_in[1];
    const float* memb    = (const float*)d_in[2];
    const float* thr     = (const float*)d_in[3];
    const float* refr_in = (const float*)d_in[4];

    char* ws = (char*)d_ws;
    uint32_t* r0nz   = (uint32_t*)(ws + OFF_R0NZ);
    uint32_t* colAny = (uint32_t*)(ws + OFF_COLANY);
    uint32_t* deg    = (uint32_t*)(ws + OFF_DEG);
    uint32_t* nbr    = (uint32_t*)(ws + OFF_NBR);
    unsigned char* sExp = (unsigned char*)(ws + OFF_SEXP);
    float*    vt     = (float*)(ws + OFF_VT);   // v state in ws (268 MB available)
    float*    out    = (float*)d_out;

    build_k<<<dim3(N_), dim3(256), 0, stream>>>(
        C, refr_in, deg, nbr, r0nz, colAny,
        (uint32_t*)(sExp + (size_t)N_ * B_),
        (uint32_t*)(sExp + SEXP_BUF + (size_t)N_ * B_));

    // step 0: writes sExp buf0, colAny row 2
    first_k<<<dim3(2048), dim3(256), 0, stream>>>(ext, memb, thr, r0nz, vt,
                                                  sExp, colAny + 2 * W_);

    for (int s = 1; s < NSTEPS_; ++s) {
        unsigned char* sprev = sExp + ((s - 1) & 1) * (size_t)SEXP_BUF;
        unsigned char* snext = sExp + (s & 1) * (size_t)SEXP_BUF;
        if (s < NSTEPS_ - 1)
            step_k<0><<<dim3(1024), dim3(256), 0, stream>>>(
                thr, deg, nbr, sprev, snext, vt,
                colAny + (s + 1) * W_,      // any(s-1)
                colAny + s * W_,            // any(s-2)
                r0nz + s * W_,
                colAny + (s + 2) * W_, out);
        else
            step_k<1><<<dim3(1024), dim3(256), 0, stream>>>(
                thr, deg, nbr, sprev, snext, vt,
                colAny + (s + 1) * W_,
                colAny + s * W_,
                r0nz + s * W_,
                colAny + (s + 2) * W_, out);
    }
}

// Round 16
// 147.354 us; speedup vs baseline: 5.1581x; 1.1471x over previous
//
#include <hip/hip_runtime.h>
#include <stdint.h>

#define N_ 4096
#define B_ 1024
#define NSTEPS_ 10
#define DEG_SLOTS 40    // padded neighbor-list slots (deg ~ Poisson(12); P(>40) ~ 1e-11)
#define UNR 16          // static unrolled gather depth (sentinel-padded)
#define PAD_E ((uint32_t)(N_ * B_))   // sentinel -> byte offset of zero pad row
#define NBLK 256
#define NCTR 16
#define FLAGI 512

// ws layout (bytes):
//   bar  : 0      .. 4224     u32[1056]: 16 ctrs at stride 32 + flag at [512]
//   deg  : 8192   .. 24576    u32[N]
//   nbr  : 24576  .. 679936   u32[N][DEG_SLOTS] entry = m*B (byte off); sentinel N*B
//   sExp : 679936 .. ~9.07MB  u8[2][(N+1)*B] spike BYTES [n][b]; row N_ always zero
#define OFF_BAR  0
#define OFF_DEG  8192
#define OFF_NBR  24576
#define OFF_SEXP 679936
#define SEXP_BUF ((N_ + 1) * B_)

// build_k: neighbor lists from C. Block 0 zeros barrier state; blocks 1,2 zero
// the sExp pad rows (all consumed only by the NEXT dispatch -> safe).
__global__ __launch_bounds__(256) void build_k(const float* __restrict__ C,
                                               uint32_t* __restrict__ deg,
                                               uint32_t* __restrict__ nbr,
                                               uint32_t* __restrict__ bar,
                                               uint32_t* __restrict__ pad0,
                                               uint32_t* __restrict__ pad1) {
    __shared__ uint32_t cnt;
    int tid = threadIdx.x;
    int n = blockIdx.x;
    if (n == 0) { for (int i = tid; i < 1056; i += 256) bar[i] = 0u; }
    else if (n == 1) { pad0[tid] = 0u; }
    else if (n == 2) { pad1[tid] = 0u; }
    if (tid == 0) cnt = 0;
    __syncthreads();
    const float4* row = (const float4*)(C + (size_t)n * N_);
    for (int j4 = tid; j4 < N_ / 4; j4 += 256) {
        float4 v = row[j4];
        int base = j4 * 4;
        #pragma unroll
        for (int q = 0; q < 4; ++q) {
            float f = (q == 0) ? v.x : (q == 1) ? v.y : (q == 2) ? v.z : v.w;
            if (f != 0.0f) {
                uint32_t p = atomicAdd(&cnt, 1u);
                uint32_t m = (uint32_t)(base + q);
                if (p < DEG_SLOTS) nbr[n * DEG_SLOTS + p] = m * (uint32_t)B_;
            }
        }
    }
    __syncthreads();
    uint32_t c = min(cnt, (uint32_t)DEG_SLOTS);
    if (tid == 0) deg[n] = c;
    if (tid < DEG_SLOTS && (uint32_t)tid >= c)
        nbr[n * DEG_SLOTS + tid] = PAD_E;
}

// Grid barrier (round-12 proven scheme @ 256 blocks): relaxed L3-homed atomics;
// exactly ONE acquire load (buffer_inv) per block per phase, after the flag.
__device__ __forceinline__ void gbar(uint32_t* bar, uint32_t phase) {
    __syncthreads();                         // all waves' spike stores acked
    int tid = threadIdx.x, bid = blockIdx.x;
    if (tid == 0)
        __hip_atomic_fetch_add(&bar[(bid & (NCTR - 1)) * 32], 1u,
                               __ATOMIC_RELAXED, __HIP_MEMORY_SCOPE_AGENT);
    if (bid == 0) {
        if (tid < NCTR) {
            uint32_t tgt = (NBLK / NCTR) * phase;
            while (__hip_atomic_load(&bar[tid * 32], __ATOMIC_RELAXED,
                                     __HIP_MEMORY_SCOPE_AGENT) < tgt)
                __builtin_amdgcn_s_sleep(2);
        }
        __syncthreads();
        if (tid == 0)
            __hip_atomic_store(&bar[FLAGI], phase,
                               __ATOMIC_RELAXED, __HIP_MEMORY_SCOPE_AGENT);
    }
    if (tid == 0) {
        while (__hip_atomic_load(&bar[FLAGI], __ATOMIC_RELAXED,
                                 __HIP_MEMORY_SCOPE_AGENT) < phase)
            __builtin_amdgcn_s_sleep(2);
        (void)__hip_atomic_load(&bar[FLAGI], __ATOMIC_ACQUIRE,  // one buffer_inv
                                __HIP_MEMORY_SCOPE_AGENT);
    }
    __syncthreads();
}

// Persistent kernel, wave-per-neuron decomposition: block = 16 neurons x ALL
// 1024 batches (1024 threads, 16 waves); grid 256 = 1 block/CU (safest
// cooperative co-residency). Wave = 1 neuron: refractory state is a wave-local
// register (one __ballot/step) -- no colAny arrays. Thread = 1 neuron x 16
// batches; v in 16 VGPRs all 10 steps (no vt traffic). Gather: one uint4
// wave-inst reads a full 1 KB spike row. Spike bytes via relaxed agent-scope
// b64 atomic stores (L3 write-through); gathers PLAIN loads freshened by the
// barrier's single acquire-inv.
__global__ __launch_bounds__(1024, 4) void persist_k(const float* __restrict__ ext,
                                                     const float* __restrict__ memb,
                                                     const float* __restrict__ thr,
                                                     const float* __restrict__ refr_in,
                                                     const uint32_t* __restrict__ deg,
                                                     const uint32_t* __restrict__ nbr,
                                                     unsigned char* __restrict__ sExp,
                                                     float* __restrict__ out,
                                                     uint32_t* bar) {
    __shared__ uint32_t s_nbr[16 * DEG_SLOTS];
    __shared__ unsigned char bt[16][1040];   // output transpose tile (padded rows)

    int bid = blockIdx.x;
    int n0 = bid * 16;
    int tid = threadIdx.x;
    int wv = tid >> 6, lane = tid & 63;      // wave wv <-> neuron n0+wv
    int n = n0 + wv;
    int bb = lane * 16;                      // this thread's 16 batches

    if (tid < 16 * DEG_SLOTS) s_nbr[tid] = nbr[(size_t)n0 * DEG_SLOTS + tid];
    __syncthreads();

    float tn = thr[n];                       // wave-uniform
    float r  = refr_in[n];                   // wave-local refractory state
    uint32_t dg = __builtin_amdgcn_readfirstlane(deg[n]);
    const uint32_t* lst = &s_nbr[wv * DEG_SLOTS];

    float v[16];
    {
        float mb = memb[n];
        #pragma unroll
        for (int i = 0; i < 16; ++i)         // column loads; lines shared across waves
            v[i] = __fadd_rn(mb, ext[(size_t)(bb + i) * N_ + n]);
    }

    uint32_t spk[4];

    // ---- step 0: external input only ----
    {
        uint32_t nb = (r != 0.0f) ? 0u : 1u;
        #pragma unroll
        for (int dw = 0; dw < 4; ++dw) {
            int sp0 = (v[dw * 4 + 0] > tn) && nb;
            int sp1 = (v[dw * 4 + 1] > tn) && nb;
            int sp2 = (v[dw * 4 + 2] > tn) && nb;
            int sp3 = (v[dw * 4 + 3] > tn) && nb;
            spk[dw] = (uint32_t)sp0 | ((uint32_t)sp1 << 8) |
                      ((uint32_t)sp2 << 16) | ((uint32_t)sp3 << 24);
            v[dw * 4 + 0] = __fmul_rn(sp0 ? 0.0f : v[dw * 4 + 0], 0.95f);
            v[dw * 4 + 1] = __fmul_rn(sp1 ? 0.0f : v[dw * 4 + 1], 0.95f);
            v[dw * 4 + 2] = __fmul_rn(sp2 ? 0.0f : v[dw * 4 + 2], 0.95f);
            v[dw * 4 + 3] = __fmul_rn(sp3 ? 0.0f : v[dw * 4 + 3], 0.95f);
        }
        unsigned long long p0 = (unsigned long long)spk[0] | ((unsigned long long)spk[1] << 32);
        unsigned long long p1 = (unsigned long long)spk[2] | ((unsigned long long)spk[3] << 32);
        unsigned long long* dst = (unsigned long long*)(sExp + (size_t)n * B_ + bb);
        __hip_atomic_store(dst,     p0, __ATOMIC_RELAXED, __HIP_MEMORY_SCOPE_AGENT);
        __hip_atomic_store(dst + 1, p1, __ATOMIC_RELAXED, __HIP_MEMORY_SCOPE_AGENT);
        int anyl = (spk[0] | spk[1] | spk[2] | spk[3]) != 0;
        int any = (__ballot(anyl) != 0ull);  // wave-uniform: any over ALL batches
        r = any ? 3.0f : r;
        r = fminf(fmaxf(__fadd_rn(r, -1.0f), 0.0f), 10.0f);
    }
    gbar(bar, 1);

    // ---- steps 1..9 ----
    unsigned char* sprev = sExp;
    unsigned char* snext = sExp + (size_t)SEXP_BUF;
    for (int s = 1; s < NSTEPS_; ++s) {
        uint32_t nb = (r != 0.0f) ? 0u : 1u;
        uint32_t a0 = 0, a1 = 0, a2 = 0, a3 = 0;
        #pragma unroll
        for (int j = 0; j < UNR; ++j) {
            uint32_t e = lst[j];             // wave-uniform LDS broadcast
            uint4 d4 = *(const uint4*)(sprev + e + bb);
            a0 += d4.x; a1 += d4.y; a2 += d4.z; a3 += d4.w;
        }
        if (dg > UNR) {                      // wave-uniform tail
            for (uint32_t j = UNR; j < dg; ++j) {
                uint32_t e = lst[j];
                uint4 d4 = *(const uint4*)(sprev + e + bb);
                a0 += d4.x; a1 += d4.y; a2 += d4.z; a3 += d4.w;
            }
        }
        uint32_t accs[4] = {a0, a1, a2, a3};
        #pragma unroll
        for (int dw = 0; dw < 4; ++dw) {
            uint32_t acc = accs[dw];
            float v0 = __fadd_rn(v[dw * 4 + 0], __fmul_rn(0.1f, (float)( acc        & 255u)));
            float v1 = __fadd_rn(v[dw * 4 + 1], __fmul_rn(0.1f, (float)((acc >>  8) & 255u)));
            float v2 = __fadd_rn(v[dw * 4 + 2], __fmul_rn(0.1f, (float)((acc >> 16) & 255u)));
            float v3 = __fadd_rn(v[dw * 4 + 3], __fmul_rn(0.1f, (float)( acc >> 24        )));
            int sp0 = (v0 > tn) && nb;
            int sp1 = (v1 > tn) && nb;
            int sp2 = (v2 > tn) && nb;
            int sp3 = (v3 > tn) && nb;
            spk[dw] = (uint32_t)sp0 | ((uint32_t)sp1 << 8) |
                      ((uint32_t)sp2 << 16) | ((uint32_t)sp3 << 24);
            if (s < NSTEPS_ - 1) {
                v[dw * 4 + 0] = __fmul_rn(sp0 ? 0.0f : v0, 0.95f);
                v[dw * 4 + 1] = __fmul_rn(sp1 ? 0.0f : v1, 0.95f);
                v[dw * 4 + 2] = __fmul_rn(sp2 ? 0.0f : v2, 0.95f);
                v[dw * 4 + 3] = __fmul_rn(sp3 ? 0.0f : v3, 0.95f);
            }
        }
        if (s < NSTEPS_ - 1) {
            unsigned long long p0 = (unsigned long long)spk[0] | ((unsigned long long)spk[1] << 32);
            unsigned long long p1 = (unsigned long long)spk[2] | ((unsigned long long)spk[3] << 32);
            unsigned long long* dst = (unsigned long long*)(snext + (size_t)n * B_ + bb);
            __hip_atomic_store(dst,     p0, __ATOMIC_RELAXED, __HIP_MEMORY_SCOPE_AGENT);
            __hip_atomic_store(dst + 1, p1, __ATOMIC_RELAXED, __HIP_MEMORY_SCOPE_AGENT);
            int anyl = (spk[0] | spk[1] | spk[2] | spk[3]) != 0;
            int any = (__ballot(anyl) != 0ull);
            r = any ? 3.0f : r;
            r = fminf(fmaxf(__fadd_rn(r, -1.0f), 0.0f), 10.0f);
            gbar(bar, (uint32_t)s + 1);
        }
        unsigned char* t = sprev; sprev = snext; snext = t;
    }

    // ---- output: step-9 spikes (in regs) -> byte tile -> [b][n] float4 ----
    *(uint4*)&bt[wv][bb] = make_uint4(spk[0], spk[1], spk[2], spk[3]);
    __syncthreads();
    #pragma unroll
    for (int p = 0; p < 4; ++p) {
        int i = tid + p * 1024;              // 4096 float4s: 1024 rows x 4 cols
        int rrow = i >> 2, c4 = (i & 3) * 4;
        float4 o;
        o.x = (float)bt[c4 + 0][rrow];
        o.y = (float)bt[c4 + 1][rrow];
        o.z = (float)bt[c4 + 2][rrow];
        o.w = (float)bt[c4 + 3][rrow];
        *(float4*)&out[(size_t)rrow * N_ + n0 + c4] = o;
    }
}

extern "C" void kernel_launch(void* const* d_in, const int* in_sizes, int n_in,
                              void* d_out, int out_size, void* d_ws, size_t ws_size,
                              hipStream_t stream) {
    const float* ext     = (const float*)d_in[0];
    const float* C       = (const float*)d_in[1];
    const float* memb    = (const float*)d_in[2];
    const float* thr     = (const float*)d_in[3];
    const float* refr_in = (const float*)d_in[4];

    char* ws = (char*)d_ws;
    uint32_t* bar    = (uint32_t*)(ws + OFF_BAR);
    uint32_t* deg    = (uint32_t*)(ws + OFF_DEG);
    uint32_t* nbr    = (uint32_t*)(ws + OFF_NBR);
    unsigned char* sExp = (unsigned char*)(ws + OFF_SEXP);
    float*    out    = (float*)d_out;

    build_k<<<dim3(N_), dim3(256), 0, stream>>>(
        C, deg, nbr, bar,
        (uint32_t*)(sExp + (size_t)N_ * B_),
        (uint32_t*)(sExp + (size_t)SEXP_BUF + (size_t)N_ * B_));

    void* args[] = {(void*)&ext, (void*)&memb, (void*)&thr, (void*)&refr_in,
                    (void*)&deg, (void*)&nbr, (void*)&sExp, (void*)&out,
                    (void*)&bar};
    hipLaunchCooperativeKernel((const void*)persist_k, dim3(NBLK), dim3(1024),
                               args, 0, stream);
}